// Round 11
// baseline (387.579 us; speedup 1.0000x reference)
//
#include <hip/hip_runtime.h>
#include <cstdint>
#include <cstddef>

// Problem constants
#define B_ 8
#define NT 1024
#define NK 1024
#define D_ 768
#define H_ 8
#define HD_ 96
#define CLS_ 20
#define L_ 1044
#define SCALE_ 0.10206207261596577f
#define LOG2E_ 1.4426950408889634f
#define TQ 16
// integer mask threshold: bits < THR  <=>  uniform(bits) < 0.3f (exact)
#define MASK_THR 1288490496u

typedef __attribute__((ext_vector_type(8))) short bf16x8;
typedef __attribute__((ext_vector_type(4))) float f32x4;

__device__ __forceinline__ unsigned short f2bf(float f) {
    uint32_t u = __float_as_uint(f);
    u += 0x7FFFu + ((u >> 16) & 1u);   // RNE (no NaN inputs here)
    return (unsigned short)(u >> 16);
}

__device__ __forceinline__ float fexp2(float x) {
#if __has_builtin(__builtin_amdgcn_exp2f)
    return __builtin_amdgcn_exp2f(x);
#else
    return __expf(x * 0.6931471805599453f);
#endif
}

// async global->LDS, 16B per lane; LDS dest = wave-uniform base + lane*16
__device__ __forceinline__ void gll16(const void* g, void* l) {
    __builtin_amdgcn_global_load_lds(
        (const __attribute__((address_space(1))) unsigned int*)g,
        (__attribute__((address_space(3))) unsigned int*)l,
        16, 0, 0);
}

// ---------------------------------------------------------------------------
// JAX threefry2x32, partitionable scheme (verified): counter = (0, g),
// output bits = x0 ^ x1. key = (0, 42).
// ---------------------------------------------------------------------------
__device__ __forceinline__ uint32_t tf_bits(uint32_t g) {
    const uint32_t k0 = 0u, k1 = 42u;
    const uint32_t ks2 = k0 ^ k1 ^ 0x1BD11BDAu;
    uint32_t x0 = 0u, x1 = g;

    x0 += k0; x1 += k1;
#define TF_ROUND(r) { x0 += x1; x1 = __builtin_rotateleft32(x1, (r)); x1 ^= x0; }
    TF_ROUND(13) TF_ROUND(15) TF_ROUND(26) TF_ROUND(6)
    x0 += k1;  x1 += ks2 + 1u;
    TF_ROUND(17) TF_ROUND(29) TF_ROUND(16) TF_ROUND(24)
    x0 += ks2; x1 += k0 + 2u;
    TF_ROUND(13) TF_ROUND(15) TF_ROUND(26) TF_ROUND(6)
    x0 += k0;  x1 += k1 + 3u;
    TF_ROUND(17) TF_ROUND(29) TF_ROUND(16) TF_ROUND(24)
    x0 += k1;  x1 += ks2 + 4u;
    TF_ROUND(13) TF_ROUND(15) TF_ROUND(26) TF_ROUND(6)
    x0 += ks2; x1 += k0 + 5u;
#undef TF_ROUND
    return x0 ^ x1;
}

// ---------------------------------------------------------------------------
// merged pre-pass: blocks < 12288 do fp32->bf16 convert of inputs;
// blocks >= 12288 do the three weight transposes (saves one launch gap).
// ---------------------------------------------------------------------------
__global__ __launch_bounds__(256) void pre_all(
    const float* __restrict__ in_q, unsigned short* __restrict__ Aq,
    const float* __restrict__ in_k, unsigned short* __restrict__ Ak,
    const float* __restrict__ Wq, const float* __restrict__ Wkv,
    const float* __restrict__ Wproj,
    unsigned short* __restrict__ Wqt, unsigned short* __restrict__ Wkvt,
    unsigned short* __restrict__ Wpt, float scaleq)
{
    const int bid = blockIdx.x;
    if (bid < 12288) {
        int i = bid * 256 + threadIdx.x;
        const float* s = in_q;
        unsigned short* dct = Aq;
        if (i >= 1572864) { i -= 1572864; s = in_k; dct = Ak; }
        float4 v = ((const float4*)s)[i];
        ushort4 o;
        o.x = f2bf(v.x); o.y = f2bf(v.y); o.z = f2bf(v.z); o.w = f2bf(v.w);
        ((ushort4*)dct)[i] = o;
        return;
    }

    // weight transpose part: decode (z, bx, by) from remaining 3456 blocks
    const int rr = bid - 12288;
    const int z  = rr / 1152;
    const int rm = rr % 1152;
    const int bx = rm % 48, by = rm / 48;

    const float* W; unsigned short* Wt; int Nn; float scale;
    if (z == 0)      { W = Wq;    Wt = Wqt;  Nn = 768;  scale = scaleq; }
    else if (z == 1) { W = Wkv;   Wt = Wkvt; Nn = 1536; scale = 1.f; }
    else             { W = Wproj; Wt = Wpt;  Nn = 768;  scale = 1.f; }
    if (bx * 32 >= Nn) return;   // whole block exits; no barrier issue

    __shared__ unsigned short tile[32][36];
    const int n0 = bx * 32, k0 = by * 32;
    const int t = threadIdx.x, r = t >> 3, c4 = (t & 7) * 4;

    float4 v = *(const float4*)&W[(size_t)(k0 + r) * Nn + n0 + c4];
    tile[r][c4 + 0] = f2bf(v.x * scale);
    tile[r][c4 + 1] = f2bf(v.y * scale);
    tile[r][c4 + 2] = f2bf(v.z * scale);
    tile[r][c4 + 3] = f2bf(v.w * scale);
    __syncthreads();

    ushort4 o;
    o.x = tile[c4 + 0][r];
    o.y = tile[c4 + 1][r];
    o.z = tile[c4 + 2][r];
    o.w = tile[c4 + 3][r];
    *(ushort4*)&Wt[(size_t)(n0 + r) * 768 + k0 + c4] = o;
}

// ---------------------------------------------------------------------------
// bf16 MFMA GEMM body, NT form, BK=64 + T2 XOR-swizzled LDS (granule g at
// row r stored at g^(r&7); source pre-swizzled per rule #21/m173 so gll16's
// linear lane-write lands each granule in its swizzled slot; ds_read applies
// the same XOR). Read banks spread over all 32 (2-way = free). MFMA k-order
// = chunk h=0 then h=1 -> bit-identical to BK=32 version.
// MODE 0: bf16 out. MODE 2: V-transpose out — write vT[(b*8+h)*96+d][n].
// ---------------------------------------------------------------------------
template <int MODE>
__device__ __forceinline__ void gemm_body(
    const unsigned short* __restrict__ A,
    const unsigned short* __restrict__ Bt,
    unsigned short* __restrict__ Cb,
    int N, int K, int bm, int bn,
    unsigned short* As, unsigned short* Bs)
{
    const int tid  = threadIdx.x;
    const int lane = tid & 63, wv = tid >> 6;
    const int mcol = lane & 15, quad = lane >> 4;
    const int wr = (wv & 1) * 64, wc = (wv >> 1) * 64;
    const int lrow = lane >> 3;                    // row within 8-row slot
    const int scol = ((lane & 7) ^ (lrow & 7)) * 8; // pre-swizzled src granule

    f32x4 acc[4][4];
#pragma unroll
    for (int i = 0; i < 4; ++i)
#pragma unroll
        for (int j = 0; j < 4; ++j) acc[i][j] = (f32x4){0.f, 0.f, 0.f, 0.f};

    for (int k0 = 0; k0 < K; k0 += 64) {
#pragma unroll
        for (int c = 0; c < 4; ++c) {              // 16 slots of 8x64; 4/wave
            const int s = wv * 4 + c;
            const int row = s * 8 + lrow;
            gll16(&A [(size_t)(bm + row) * K + k0 + scol], &As[s * 512]);
            gll16(&Bt[(size_t)(bn + row) * K + k0 + scol], &Bs[s * 512]);
        }
        __syncthreads();

#pragma unroll
        for (int h = 0; h < 2; ++h) {
            bf16x8 af[4], bfr[4];
#pragma unroll
            for (int i = 0; i < 4; ++i) {
                const int ra = wr + i * 16 + mcol;
                const int rb = wc + i * 16 + mcol;
                af[i]  = *(const bf16x8*)&As[ra * 64 + ((h * 4 + quad) ^ (ra & 7)) * 8];
                bfr[i] = *(const bf16x8*)&Bs[rb * 64 + ((h * 4 + quad) ^ (rb & 7)) * 8];
            }
#pragma unroll
            for (int i = 0; i < 4; ++i)
#pragma unroll
                for (int j = 0; j < 4; ++j)
                    acc[i][j] = __builtin_amdgcn_mfma_f32_16x16x32_bf16(af[i], bfr[j], acc[i][j], 0, 0, 0);
        }
        __syncthreads();
    }

    if (MODE == 2) {
        // V-transpose epilogue: Cb plays the role of vT.
#pragma unroll
        for (int j = 0; j < 4; ++j) {
            const int cv = (bn - 768) + wc + j * 16 + mcol;   // 0..767
            const int hV = cv / 96, dV = cv % 96;
#pragma unroll
            for (int i = 0; i < 4; ++i) {
                const int rrow = bm + wr + i * 16 + quad * 4;  // rg base; same b for all 4
                const int bb = rrow >> 10, nn = rrow & 1023;
                ushort4 o;
                o.x = f2bf(acc[i][j][0]); o.y = f2bf(acc[i][j][1]);
                o.z = f2bf(acc[i][j][2]); o.w = f2bf(acc[i][j][3]);
                *(ushort4*)&Cb[((size_t)(bb * 8 + hV) * 96 + dV) * 1024 + nn] = o;
            }
        }
        return;
    }

#pragma unroll
    for (int j = 0; j < 4; ++j) {
        const int col = bn + wc + j * 16 + mcol;
#pragma unroll
        for (int i = 0; i < 4; ++i)
#pragma unroll
            for (int rg = 0; rg < 4; ++rg) {
                const int rrow = bm + wr + i * 16 + quad * 4 + rg;
                Cb[(size_t)rrow * N + col] = f2bf(acc[i][j][rg]);
            }
    }
}

// fused Q + K + V projection GEMM, XCD-clustered 1D grid (1152 blocks):
// xcd = bid&7 owns y-panel group [xcd*8, xcd*8+8) -> A panels L2-resident.
// bx 0..5 -> qb (Q), 6..11 -> kv16 K-half, 12..17 -> vT (transposed V)
__global__ __launch_bounds__(256) void mfma_gemm_qkv(
    const unsigned short* __restrict__ Aq, const unsigned short* __restrict__ Ak,
    const unsigned short* __restrict__ Wqt, const unsigned short* __restrict__ Wkvt,
    unsigned short* __restrict__ qb, unsigned short* __restrict__ kv16,
    unsigned short* __restrict__ vT)
{
    __shared__ unsigned short As[128 * 64];
    __shared__ unsigned short Bs[128 * 64];
    const int bid = blockIdx.x;
    const int xcd = bid & 7, idx = bid >> 3;      // idx in [0,144)
    const int by  = xcd * 8 + idx / 18;           // 0..63
    const int bx  = idx % 18;
    const int bm  = by * 128;
    if (bx < 6)
        gemm_body<0>(Aq, Wqt, qb, 768, 768, bm, bx * 128, As, Bs);
    else if (bx < 12)
        gemm_body<0>(Ak, Wkvt, kv16, 1536, 768, bm, (bx - 6) * 128, As, Bs);
    else
        gemm_body<2>(Ak, Wkvt, vT, 0, 768, bm, (bx - 12) * 128 + 768, As, Bs);
}

// ---------------------------------------------------------------------------
// final projection GEMM: 64x128 tiles (768 blocks = exactly 3/CU), split-A
// (A + Alo) fp32 out + bias, BK=64 + same swizzle. XCD-clustered.
// Wave wv: rows [(wv&1)*32, +32), cols [(wv>>1)*64, +64); acc[2][4].
// ---------------------------------------------------------------------------
__global__ __launch_bounds__(256) void mfma_gemm_proj(
    const unsigned short* __restrict__ A, const unsigned short* __restrict__ Alo,
    const unsigned short* __restrict__ Bt, const float* __restrict__ bias,
    float* __restrict__ Cf)
{
    __shared__ unsigned short As [64 * 64];
    __shared__ unsigned short Als[64 * 64];
    __shared__ unsigned short Bs [128 * 64];

    const int bid = blockIdx.x;                   // 768 blocks
    const int xcd = bid & 7, idx = bid >> 3;      // idx in [0,96)
    const int by  = xcd * 16 + idx / 6;           // 0..127
    const int bx  = idx % 6;                      // 0..5
    const int bm  = by * 64, bn = bx * 128;

    const int tid  = threadIdx.x;
    const int lane = tid & 63, wv = tid >> 6;
    const int mcol = lane & 15, quad = lane >> 4;
    const int wr = (wv & 1) * 32, wc = (wv >> 1) * 64;
    const int lrow = lane >> 3;
    const int scol = ((lane & 7) ^ (lrow & 7)) * 8;

    f32x4 acc[2][4];
#pragma unroll
    for (int i = 0; i < 2; ++i)
#pragma unroll
        for (int j = 0; j < 4; ++j) acc[i][j] = (f32x4){0.f, 0.f, 0.f, 0.f};

    for (int k0 = 0; k0 < 768; k0 += 64) {
#pragma unroll
        for (int c = 0; c < 2; ++c) {              // A/Alo: 8 slots, 2/wave
            const int s = wv * 2 + c;
            const int row = s * 8 + lrow;
            gll16(&A  [(size_t)(bm + row) * 768 + k0 + scol], &As [s * 512]);
            gll16(&Alo[(size_t)(bm + row) * 768 + k0 + scol], &Als[s * 512]);
        }
#pragma unroll
        for (int c = 0; c < 4; ++c) {              // B: 16 slots, 4/wave
            const int s = wv * 4 + c;
            const int row = s * 8 + lrow;
            gll16(&Bt[(size_t)(bn + row) * 768 + k0 + scol], &Bs[s * 512]);
        }
        __syncthreads();

#pragma unroll
        for (int h = 0; h < 2; ++h) {
            bf16x8 af[2], al[2], bfr[4];
#pragma unroll
            for (int i = 0; i < 2; ++i) {
                const int ra = wr + i * 16 + mcol;
                const int go = ((h * 4 + quad) ^ (ra & 7)) * 8;
                af[i] = *(const bf16x8*)&As [ra * 64 + go];
                al[i] = *(const bf16x8*)&Als[ra * 64 + go];
            }
#pragma unroll
            for (int j = 0; j < 4; ++j) {
                const int rb = wc + j * 16 + mcol;
                bfr[j] = *(const bf16x8*)&Bs[rb * 64 + ((h * 4 + quad) ^ (rb & 7)) * 8];
            }
#pragma unroll
            for (int i = 0; i < 2; ++i)
#pragma unroll
                for (int j = 0; j < 4; ++j) {
                    acc[i][j] = __builtin_amdgcn_mfma_f32_16x16x32_bf16(af[i], bfr[j], acc[i][j], 0, 0, 0);
                    acc[i][j] = __builtin_amdgcn_mfma_f32_16x16x32_bf16(al[i], bfr[j], acc[i][j], 0, 0, 0);
                }
        }
        __syncthreads();
    }

#pragma unroll
    for (int j = 0; j < 4; ++j) {
        const int col = bn + wc + j * 16 + mcol;
        const float bs = bias[col];
#pragma unroll
        for (int i = 0; i < 2; ++i)
#pragma unroll
            for (int rg = 0; rg < 4; ++rg) {
                const int rrow = bm + wr + i * 16 + quad * 4 + rg;
                Cf[(size_t)rrow * 768 + col] = acc[i][j][rg] + bs;
            }
    }
}

// ---------------------------------------------------------------------------
// Attention v12: chunk-interleaved front phase. 4 chunks of 4 nt:
// {issue 12 MFMA (async)} -> {threefry for the chunk (rolled, pure VALU,
// hides MFMA+K-load latency)} -> {exp2 on now-ready accumulators}.
// All d[] indices compile-time (no scratch). 2 barriers; shift-0 softmax.
// ---------------------------------------------------------------------------
__global__ __launch_bounds__(256, 4) void attn_kernel(
    const unsigned short* __restrict__ qb, const unsigned short* __restrict__ kv16,
    const unsigned short* __restrict__ vT,
    unsigned short* __restrict__ xh, unsigned short* __restrict__ xl)
{
    const int j    = blockIdx.x;
    const int bh   = ((j >> 9) << 3) | (j & 7);
    const int tile = (j >> 3) & 63;
    const int h    = bh & 7;
    const int b    = bh >> 3;
    const int lq0  = tile * TQ;
    const int tid  = threadIdx.x;
    const int lane = tid & 63;
    const int wv   = tid >> 6;          // 0..3
    const int mcol = lane & 15;
    const int quad = lane >> 4;
    const int row0 = quad * 4;          // first of this lane's 4 C-rows

    __shared__ __align__(16) unsigned short sPb[16 * 1032];   // 33 KB
    __shared__ float sS1[4][16], sS2[4][16];
    __shared__ float sCs[16];

    f32x4 d[16];
    float ps[4] = {0.f, 0.f, 0.f, 0.f}, cs[4] = {0.f, 0.f, 0.f, 0.f};
    uint32_t m0 = 0u, m1 = 0u;
    {
        const size_t qrow = ((size_t)(b * NT) + lq0 + mcol) * 768 + h * 96 + quad * 8;
        const bf16x8 qa0 = *(const bf16x8*)&qb[qrow];
        const bf16x8 qa1 = *(const bf16x8*)&qb[qrow + 32];
        const bf16x8 qa2 = *(const bf16x8*)&qb[qrow + 64];
        const unsigned short* kvb = kv16 + (size_t)(b * NK) * 1536 + h * 96;
        const uint32_t rowg =
            ((uint32_t)(b * 8 + h) * (uint32_t)L_ + (uint32_t)(lq0 + row0 + CLS_)) * 1024u;

#pragma unroll
        for (int c = 0; c < 4; ++c) {
            // --- QK MFMA for nt = 4c..4c+3 (issued, results pending) ---
#pragma unroll
            for (int u = 0; u < 4; ++u) {
                const int nt = c * 4 + u;
                const int koff = ((wv * 16 + nt) * 16 + mcol) * 1536 + quad * 8;
                f32x4 acc = {0.f, 0.f, 0.f, 0.f};
                acc = __builtin_amdgcn_mfma_f32_16x16x32_bf16(qa0, *(const bf16x8*)&kvb[koff],      acc, 0, 0, 0);
                acc = __builtin_amdgcn_mfma_f32_16x16x32_bf16(qa1, *(const bf16x8*)&kvb[koff + 32], acc, 0, 0, 0);
                acc = __builtin_amdgcn_mfma_f32_16x16x32_bf16(qa2, *(const bf16x8*)&kvb[koff + 64], acc, 0, 0, 0);
                d[nt] = acc;
            }
            // --- threefry for nt = 4c..4c+3 (rolled; hides MFMA latency) ---
#pragma unroll 1
            for (int nt = c * 4; nt < c * 4 + 4; ++nt) {
                const uint32_t col = (uint32_t)(((wv * 16 + nt) << 4) + mcol);
                uint32_t accb = 0u;
#pragma unroll
                for (int rg = 0; rg < 4; ++rg) {
                    uint32_t bits = tf_bits(rowg + 1024u * (uint32_t)rg + col);
                    accb |= (bits < MASK_THR ? 1u : 0u) << rg;
                }
                if (nt < 8) m0 |= accb << (nt * 4);
                else        m1 |= accb << ((nt - 8) * 4);
            }
            // --- exp2 (shift 0) on now-ready accumulators + partial sums ---
#pragma unroll
            for (int u = 0; u < 4; ++u) {
                const int nt = c * 4 + u;
                const bool c_all = (wv == 0 && nt == 0);
                const bool c_few = (wv == 0 && nt == 1);
#pragma unroll
                for (int rg = 0; rg < 4; ++rg) {
                    const bool iscls = c_all || (c_few && mcol < 4);
                    float e = fexp2(d[nt][rg]);
                    d[nt][rg] = e;
                    if (iscls) cs[rg] += e; else ps[rg] += e;
                }
            }
        }
    }

    // ---- cross-lane sum reduce ----
#pragma unroll
    for (int rg = 0; rg < 4; ++rg)
#pragma unroll
        for (int m = 1; m <= 8; m <<= 1) ps[rg] += __shfl_xor(ps[rg], m);
    if (mcol == 0)
#pragma unroll
        for (int rg = 0; rg < 4; ++rg) sS1[wv][row0 + rg] = ps[rg];
    if (wv == 0) {
#pragma unroll
        for (int rg = 0; rg < 4; ++rg)
#pragma unroll
            for (int m = 1; m <= 8; m <<= 1) cs[rg] += __shfl_xor(cs[rg], m);
        if (mcol == 0)
#pragma unroll
            for (int rg = 0; rg < 4; ++rg) sCs[row0 + rg] = cs[rg];
    }
    __syncthreads();

    // 1/S with log2e folded in: e2 = exp2(e1 * (log2e/S)) = exp(p)
    float ipl[4], icl[4];
#pragma unroll
    for (int rg = 0; rg < 4; ++rg) {
        const int rr = row0 + rg;
        float s = sS1[0][rr] + sS1[1][rr] + sS1[2][rr] + sS1[3][rr];
        ipl[rg] = LOG2E_ / s;
        icl[rg] = LOG2E_ / sCs[rr];
    }

    // ---- fused: probs -> mask -> exp (shift 0) -> bf16 store + s2 partials ----
    float s2[4] = {0.f, 0.f, 0.f, 0.f};
#pragma unroll
    for (int nt = 0; nt < 16; ++nt) {
        const bool c_all = (wv == 0 && nt == 0);
        const bool c_few = (wv == 0 && nt == 1);
        const int col = (wv * 16 + nt) * 16 + mcol;
#pragma unroll
        for (int rg = 0; rg < 4; ++rg) {
            const bool iscls = c_all || (c_few && mcol < 4);
            float e2 = fexp2(d[nt][rg] * (iscls ? icl[rg] : ipl[rg]));
            const int i = nt * 4 + rg;
            const uint32_t bit = (i < 32) ? (m0 >> i) : (m1 >> (i - 32));
            e2 = (bit & 1u) ? 0.f : e2;       // == exp(p - 1e12) underflow
            s2[rg] += e2;
            sPb[(row0 + rg) * 1032 + col] = f2bf(e2);
        }
    }
#pragma unroll
    for (int rg = 0; rg < 4; ++rg)
#pragma unroll
        for (int m = 1; m <= 8; m <<= 1) s2[rg] += __shfl_xor(s2[rg], m);
    if (mcol == 0)
#pragma unroll
        for (int rg = 0; rg < 4; ++rg) sS2[wv][row0 + rg] = s2[rg];
    __syncthreads();

    // ---- PV via MFMA: wave wv owns d-tiles {wv, wv+4 (if <6)} ----
    {
        const int t0 = wv, t1 = wv + 4;
        const size_t vbase = ((size_t)(b * 8 + h)) * 96 * 1024;
        f32x4 a0 = {0.f, 0.f, 0.f, 0.f};
        f32x4 a1 = {0.f, 0.f, 0.f, 0.f};
        __builtin_amdgcn_s_setprio(1);
#pragma unroll 4
        for (int k0 = 0; k0 < 1024; k0 += 32) {
            const bf16x8 pa = *(const bf16x8*)&sPb[mcol * 1032 + k0 + quad * 8];
            const size_t v0 = vbase + (size_t)(t0 * 16 + mcol) * 1024 + k0 + quad * 8;
            a0 = __builtin_amdgcn_mfma_f32_16x16x32_bf16(pa, *(const bf16x8*)&vT[v0], a0, 0, 0, 0);
            if (t1 < 6) {
                const size_t v1 = vbase + (size_t)(t1 * 16 + mcol) * 1024 + k0 + quad * 8;
                a1 = __builtin_amdgcn_mfma_f32_16x16x32_bf16(pa, *(const bf16x8*)&vT[v1], a1, 0, 0, 0);
            }
        }
        __builtin_amdgcn_s_setprio(0);

        float inv[4];
#pragma unroll
        for (int rg = 0; rg < 4; ++rg) {
            const int rr = row0 + rg;
            inv[rg] = 1.f / (sS2[0][rr] + sS2[1][rr] + sS2[2][rr] + sS2[3][rr]);
        }
#pragma unroll
        for (int rg = 0; rg < 4; ++rg) {
            const size_t ob = ((size_t)(b * NT) + lq0 + row0 + rg) * 768 + h * 96;
            {
                float val = a0[rg] * inv[rg];
                unsigned short hb = f2bf(val);
                xh[ob + t0 * 16 + mcol] = hb;
                xl[ob + t0 * 16 + mcol] = f2bf(val - __uint_as_float((uint32_t)hb << 16));
            }
            if (t1 < 6) {
                float val = a1[rg] * inv[rg];
                unsigned short hb = f2bf(val);
                xh[ob + t1 * 16 + mcol] = hb;
                xl[ob + t1 * 16 + mcol] = f2bf(val - __uint_as_float((uint32_t)hb << 16));
            }
        }
    }
}

// ---------------------------------------------------------------------------
extern "C" void kernel_launch(void* const* d_in, const int* in_sizes, int n_in,
                              void* d_out, int out_size, void* d_ws, size_t ws_size,
                              hipStream_t stream)
{
    const float* in_q   = (const float*)d_in[0];
    const float* in_k   = (const float*)d_in[1];
    const float* Wq     = (const float*)d_in[2];
    const float* Wkv    = (const float*)d_in[3];
    // d_in[4] = Wcls — unused (cls query rows are dropped by the reference)
    const float* Wproj  = (const float*)d_in[5];
    const float* bproj  = (const float*)d_in[6];
    float* out = (float*)d_out;

    // workspace layout (bf16 units)
    unsigned short* ws16 = (unsigned short*)d_ws;
    unsigned short* Aq   = ws16;                  // 6291456
    unsigned short* Ak   = Aq   + 6291456;        // 6291456
    unsigned short* qb   = Ak   + 6291456;        // 6291456
    unsigned short* kv16 = qb   + 6291456;        // 12582912 (V half unused)
    unsigned short* vT   = kv16 + 12582912;       // 6291456
    unsigned short* Wqt  = vT   + 6291456;        // 589824
    unsigned short* Wkvt = Wqt  + 589824;         // 1179648
    unsigned short* Wpt  = Wkvt + 1179648;        // 589824
    unsigned short* xh   = Aq;                    // reuse (dead after gemm_qkv)
    unsigned short* xl   = Ak;                    // reuse (dead after gemm_qkv)

    dim3 blk(256);

    // SCALE * log2e folded into Wq so QK logits are in exp2 domain
    pre_all<<<15744, blk, 0, stream>>>(
        in_q, Aq, in_k, Ak, Wq, Wkv, Wproj, Wqt, Wkvt, Wpt, SCALE_ * LOG2E_);

    mfma_gemm_qkv<<<1152, blk, 0, stream>>>(
        Aq, Ak, Wqt, Wkvt, qb, kv16, vT);

    attn_kernel<<<4096, blk, 0, stream>>>(qb, kv16, vT, xh, xl);

    mfma_gemm_proj<<<768, blk, 0, stream>>>(
        xh, xl, Wpt, bproj, out);
}

// Round 12
// 383.232 us; speedup vs baseline: 1.0113x; 1.0113x over previous
//
#include <hip/hip_runtime.h>
#include <cstdint>
#include <cstddef>

// Problem constants
#define B_ 8
#define NT 1024
#define NK 1024
#define D_ 768
#define H_ 8
#define HD_ 96
#define CLS_ 20
#define L_ 1044
#define SCALE_ 0.10206207261596577f
#define LOG2E_ 1.4426950408889634f
#define TQ 16
// integer mask threshold: bits < THR  <=>  uniform(bits) < 0.3f (exact)
#define MASK_THR 1288490496u

typedef __attribute__((ext_vector_type(8))) short bf16x8;
typedef __attribute__((ext_vector_type(4))) float f32x4;

__device__ __forceinline__ unsigned short f2bf(float f) {
    uint32_t u = __float_as_uint(f);
    u += 0x7FFFu + ((u >> 16) & 1u);   // RNE (no NaN inputs here)
    return (unsigned short)(u >> 16);
}

__device__ __forceinline__ float fexp2(float x) {
#if __has_builtin(__builtin_amdgcn_exp2f)
    return __builtin_amdgcn_exp2f(x);
#else
    return __expf(x * 0.6931471805599453f);
#endif
}

// async global->LDS, 16B per lane; LDS dest = wave-uniform base + lane*16
__device__ __forceinline__ void gll16(const void* g, void* l) {
    __builtin_amdgcn_global_load_lds(
        (const __attribute__((address_space(1))) unsigned int*)g,
        (__attribute__((address_space(3))) unsigned int*)l,
        16, 0, 0);
}

// ---------------------------------------------------------------------------
// JAX threefry2x32, partitionable scheme (verified): counter = (0, g),
// output bits = x0 ^ x1. key = (0, 42).
// ---------------------------------------------------------------------------
__device__ __forceinline__ uint32_t tf_bits(uint32_t g) {
    const uint32_t k0 = 0u, k1 = 42u;
    const uint32_t ks2 = k0 ^ k1 ^ 0x1BD11BDAu;
    uint32_t x0 = 0u, x1 = g;

    x0 += k0; x1 += k1;
#define TF_ROUND(r) { x0 += x1; x1 = __builtin_rotateleft32(x1, (r)); x1 ^= x0; }
    TF_ROUND(13) TF_ROUND(15) TF_ROUND(26) TF_ROUND(6)
    x0 += k1;  x1 += ks2 + 1u;
    TF_ROUND(17) TF_ROUND(29) TF_ROUND(16) TF_ROUND(24)
    x0 += ks2; x1 += k0 + 2u;
    TF_ROUND(13) TF_ROUND(15) TF_ROUND(26) TF_ROUND(6)
    x0 += k0;  x1 += k1 + 3u;
    TF_ROUND(17) TF_ROUND(29) TF_ROUND(16) TF_ROUND(24)
    x0 += k1;  x1 += ks2 + 4u;
    TF_ROUND(13) TF_ROUND(15) TF_ROUND(26) TF_ROUND(6)
    x0 += ks2; x1 += k0 + 5u;
#undef TF_ROUND
    return x0 ^ x1;
}

// ---------------------------------------------------------------------------
// merged pre-pass: blocks < 12288 do fp32->bf16 convert of inputs;
// blocks >= 12288 do the three weight transposes (saves one launch gap).
// ---------------------------------------------------------------------------
__global__ __launch_bounds__(256) void pre_all(
    const float* __restrict__ in_q, unsigned short* __restrict__ Aq,
    const float* __restrict__ in_k, unsigned short* __restrict__ Ak,
    const float* __restrict__ Wq, const float* __restrict__ Wkv,
    const float* __restrict__ Wproj,
    unsigned short* __restrict__ Wqt, unsigned short* __restrict__ Wkvt,
    unsigned short* __restrict__ Wpt, float scaleq)
{
    const int bid = blockIdx.x;
    if (bid < 12288) {
        int i = bid * 256 + threadIdx.x;
        const float* s = in_q;
        unsigned short* dct = Aq;
        if (i >= 1572864) { i -= 1572864; s = in_k; dct = Ak; }
        float4 v = ((const float4*)s)[i];
        ushort4 o;
        o.x = f2bf(v.x); o.y = f2bf(v.y); o.z = f2bf(v.z); o.w = f2bf(v.w);
        ((ushort4*)dct)[i] = o;
        return;
    }

    // weight transpose part: decode (z, bx, by) from remaining 3456 blocks
    const int rr = bid - 12288;
    const int z  = rr / 1152;
    const int rm = rr % 1152;
    const int bx = rm % 48, by = rm / 48;

    const float* W; unsigned short* Wt; int Nn; float scale;
    if (z == 0)      { W = Wq;    Wt = Wqt;  Nn = 768;  scale = scaleq; }
    else if (z == 1) { W = Wkv;   Wt = Wkvt; Nn = 1536; scale = 1.f; }
    else             { W = Wproj; Wt = Wpt;  Nn = 768;  scale = 1.f; }
    if (bx * 32 >= Nn) return;   // whole block exits; no barrier issue

    __shared__ unsigned short tile[32][36];
    const int n0 = bx * 32, k0 = by * 32;
    const int t = threadIdx.x, r = t >> 3, c4 = (t & 7) * 4;

    float4 v = *(const float4*)&W[(size_t)(k0 + r) * Nn + n0 + c4];
    tile[r][c4 + 0] = f2bf(v.x * scale);
    tile[r][c4 + 1] = f2bf(v.y * scale);
    tile[r][c4 + 2] = f2bf(v.z * scale);
    tile[r][c4 + 3] = f2bf(v.w * scale);
    __syncthreads();

    ushort4 o;
    o.x = tile[c4 + 0][r];
    o.y = tile[c4 + 1][r];
    o.z = tile[c4 + 2][r];
    o.w = tile[c4 + 3][r];
    *(ushort4*)&Wt[(size_t)(n0 + r) * 768 + k0 + c4] = o;
}

// ---------------------------------------------------------------------------
// bf16 MFMA GEMM body, NT form: C[M,N] = A[M,K] @ Bt[N,K]^T. BK=32
// (best-measured config; BK=64+swizzle was null-to-negative in round 11).
// MODE 0: bf16 out. MODE 2: V-transpose out — write vT[(b*8+h)*96+d][n].
// ---------------------------------------------------------------------------
template <int MODE>
__device__ __forceinline__ void gemm_body(
    const unsigned short* __restrict__ A,
    const unsigned short* __restrict__ Bt,
    unsigned short* __restrict__ Cb,
    int N, int K, int bm, int bn,
    unsigned short* As, unsigned short* Bs)
{
    const int tid  = threadIdx.x;
    const int lane = tid & 63, wv = tid >> 6;
    const int mcol = lane & 15, quad = lane >> 4;
    const int wr = (wv & 1) * 64, wc = (wv >> 1) * 64;
    const int srow = lane >> 2;
    const int skch = (lane & 3) * 8;

    f32x4 acc[4][4];
#pragma unroll
    for (int i = 0; i < 4; ++i)
#pragma unroll
        for (int j = 0; j < 4; ++j) acc[i][j] = (f32x4){0.f, 0.f, 0.f, 0.f};

    for (int k0 = 0; k0 < K; k0 += 32) {
#pragma unroll
        for (int c = 0; c < 2; ++c) {
            const int s = wv * 2 + c;
            const int row = s * 16 + srow;
            gll16(&A [(size_t)(bm + row) * K + k0 + skch], &As[s * 512]);
            gll16(&Bt[(size_t)(bn + row) * K + k0 + skch], &Bs[s * 512]);
        }
        __syncthreads();

        bf16x8 af[4], bfr[4];
#pragma unroll
        for (int i = 0; i < 4; ++i) {
            af[i]  = *(const bf16x8*)&As[(wr + i * 16 + mcol) * 32 + quad * 8];
            bfr[i] = *(const bf16x8*)&Bs[(wc + i * 16 + mcol) * 32 + quad * 8];
        }
#pragma unroll
        for (int i = 0; i < 4; ++i)
#pragma unroll
            for (int j = 0; j < 4; ++j)
                acc[i][j] = __builtin_amdgcn_mfma_f32_16x16x32_bf16(af[i], bfr[j], acc[i][j], 0, 0, 0);
        __syncthreads();
    }

    if (MODE == 2) {
        // V-transpose epilogue: Cb plays the role of vT.
#pragma unroll
        for (int j = 0; j < 4; ++j) {
            const int cv = (bn - 768) + wc + j * 16 + mcol;   // 0..767
            const int hV = cv / 96, dV = cv % 96;
#pragma unroll
            for (int i = 0; i < 4; ++i) {
                const int rrow = bm + wr + i * 16 + quad * 4;  // rg base; same b for all 4
                const int bb = rrow >> 10, nn = rrow & 1023;
                ushort4 o;
                o.x = f2bf(acc[i][j][0]); o.y = f2bf(acc[i][j][1]);
                o.z = f2bf(acc[i][j][2]); o.w = f2bf(acc[i][j][3]);
                *(ushort4*)&Cb[((size_t)(bb * 8 + hV) * 96 + dV) * 1024 + nn] = o;
            }
        }
        return;
    }

#pragma unroll
    for (int j = 0; j < 4; ++j) {
        const int col = bn + wc + j * 16 + mcol;
#pragma unroll
        for (int i = 0; i < 4; ++i)
#pragma unroll
            for (int rg = 0; rg < 4; ++rg) {
                const int rrow = bm + wr + i * 16 + quad * 4 + rg;
                Cb[(size_t)rrow * N + col] = f2bf(acc[i][j][rg]);
            }
    }
}

// fused Q + K + V projection GEMM, XCD-clustered 1D grid (1152 blocks):
// xcd = bid&7 owns y-panel group [xcd*8, xcd*8+8) -> A panels L2-resident.
// bx 0..5 -> qb (Q), 6..11 -> kv16 K-half, 12..17 -> vT (transposed V)
__global__ __launch_bounds__(256) void mfma_gemm_qkv(
    const unsigned short* __restrict__ Aq, const unsigned short* __restrict__ Ak,
    const unsigned short* __restrict__ Wqt, const unsigned short* __restrict__ Wkvt,
    unsigned short* __restrict__ qb, unsigned short* __restrict__ kv16,
    unsigned short* __restrict__ vT)
{
    __shared__ unsigned short As[128 * 32];
    __shared__ unsigned short Bs[128 * 32];
    const int bid = blockIdx.x;
    const int xcd = bid & 7, idx = bid >> 3;      // idx in [0,144)
    const int by  = xcd * 8 + idx / 18;           // 0..63
    const int bx  = idx % 18;
    const int bm  = by * 128;
    if (bx < 6)
        gemm_body<0>(Aq, Wqt, qb, 768, 768, bm, bx * 128, As, Bs);
    else if (bx < 12)
        gemm_body<0>(Ak, Wkvt, kv16, 1536, 768, bm, (bx - 6) * 128, As, Bs);
    else
        gemm_body<2>(Ak, Wkvt, vT, 0, 768, bm, (bx - 12) * 128 + 768, As, Bs);
}

// ---------------------------------------------------------------------------
// final projection GEMM: 64x128 tiles (768 blocks = exactly 3/CU, 100%
// balance vs 75% at 128x128/384), split-A (A + Alo) fp32 out + bias.
// XCD-clustered: xcd owns y-panels [xcd*16, xcd*16+16).
// Wave wv: rows [(wv&1)*32, +32), cols [(wv>>1)*64, +64); acc[2][4].
// ---------------------------------------------------------------------------
__global__ __launch_bounds__(256) void mfma_gemm_proj(
    const unsigned short* __restrict__ A, const unsigned short* __restrict__ Alo,
    const unsigned short* __restrict__ Bt, const float* __restrict__ bias,
    float* __restrict__ Cf)
{
    __shared__ unsigned short As [64 * 32];
    __shared__ unsigned short Als[64 * 32];
    __shared__ unsigned short Bs [128 * 32];

    const int bid = blockIdx.x;                   // 768 blocks
    const int xcd = bid & 7, idx = bid >> 3;      // idx in [0,96)
    const int by  = xcd * 16 + idx / 6;           // 0..127
    const int bx  = idx % 6;                      // 0..5
    const int bm  = by * 64, bn = bx * 128;

    const int tid  = threadIdx.x;
    const int lane = tid & 63, wv = tid >> 6;
    const int mcol = lane & 15, quad = lane >> 4;
    const int wr = (wv & 1) * 32, wc = (wv >> 1) * 64;
    const int srow = lane >> 2;
    const int skch = (lane & 3) * 8;

    f32x4 acc[2][4];
#pragma unroll
    for (int i = 0; i < 2; ++i)
#pragma unroll
        for (int j = 0; j < 4; ++j) acc[i][j] = (f32x4){0.f, 0.f, 0.f, 0.f};

    for (int k0 = 0; k0 < 768; k0 += 32) {
        {
            const int rowA = wv * 16 + srow;                 // A/Alo slot wv
            gll16(&A  [(size_t)(bm + rowA) * 768 + k0 + skch], &As [wv * 512]);
            gll16(&Alo[(size_t)(bm + rowA) * 768 + k0 + skch], &Als[wv * 512]);
#pragma unroll
            for (int c = 0; c < 2; ++c) {                    // B slots 2wv,2wv+1
                const int s = wv * 2 + c;
                const int row = s * 16 + srow;
                gll16(&Bt[(size_t)(bn + row) * 768 + k0 + skch], &Bs[s * 512]);
            }
        }
        __syncthreads();

        bf16x8 af[2], al[2], bfr[4];
#pragma unroll
        for (int i = 0; i < 2; ++i) {
            af[i] = *(const bf16x8*)&As [(wr + i * 16 + mcol) * 32 + quad * 8];
            al[i] = *(const bf16x8*)&Als[(wr + i * 16 + mcol) * 32 + quad * 8];
        }
#pragma unroll
        for (int j = 0; j < 4; ++j)
            bfr[j] = *(const bf16x8*)&Bs[(wc + j * 16 + mcol) * 32 + quad * 8];
#pragma unroll
        for (int i = 0; i < 2; ++i)
#pragma unroll
            for (int j = 0; j < 4; ++j) {
                acc[i][j] = __builtin_amdgcn_mfma_f32_16x16x32_bf16(af[i], bfr[j], acc[i][j], 0, 0, 0);
                acc[i][j] = __builtin_amdgcn_mfma_f32_16x16x32_bf16(al[i], bfr[j], acc[i][j], 0, 0, 0);
            }
        __syncthreads();
    }

#pragma unroll
    for (int j = 0; j < 4; ++j) {
        const int col = bn + wc + j * 16 + mcol;
        const float bs = bias[col];
#pragma unroll
        for (int i = 0; i < 2; ++i)
#pragma unroll
            for (int rg = 0; rg < 4; ++rg) {
                const int rrow = bm + wr + i * 16 + quad * 4 + rg;
                Cf[(size_t)rrow * 768 + col] = acc[i][j][rg] + bs;
            }
    }
}

// ---------------------------------------------------------------------------
// Attention v12: chunk-interleaved front phase. 4 chunks of 4 nt:
// {issue 12 MFMA (async)} -> {threefry for the chunk (rolled, pure VALU,
// hides MFMA+K-load latency)} -> {exp2 on now-ready accumulators}.
// All d[] indices compile-time (no scratch). 2 barriers; shift-0 softmax.
// ---------------------------------------------------------------------------
__global__ __launch_bounds__(256, 4) void attn_kernel(
    const unsigned short* __restrict__ qb, const unsigned short* __restrict__ kv16,
    const unsigned short* __restrict__ vT,
    unsigned short* __restrict__ xh, unsigned short* __restrict__ xl)
{
    const int j    = blockIdx.x;
    const int bh   = ((j >> 9) << 3) | (j & 7);
    const int tile = (j >> 3) & 63;
    const int h    = bh & 7;
    const int b    = bh >> 3;
    const int lq0  = tile * TQ;
    const int tid  = threadIdx.x;
    const int lane = tid & 63;
    const int wv   = tid >> 6;          // 0..3
    const int mcol = lane & 15;
    const int quad = lane >> 4;
    const int row0 = quad * 4;          // first of this lane's 4 C-rows

    __shared__ __align__(16) unsigned short sPb[16 * 1032];   // 33 KB
    __shared__ float sS1[4][16], sS2[4][16];
    __shared__ float sCs[16];

    f32x4 d[16];
    float ps[4] = {0.f, 0.f, 0.f, 0.f}, cs[4] = {0.f, 0.f, 0.f, 0.f};
    uint32_t m0 = 0u, m1 = 0u;
    {
        const size_t qrow = ((size_t)(b * NT) + lq0 + mcol) * 768 + h * 96 + quad * 8;
        const bf16x8 qa0 = *(const bf16x8*)&qb[qrow];
        const bf16x8 qa1 = *(const bf16x8*)&qb[qrow + 32];
        const bf16x8 qa2 = *(const bf16x8*)&qb[qrow + 64];
        const unsigned short* kvb = kv16 + (size_t)(b * NK) * 1536 + h * 96;
        const uint32_t rowg =
            ((uint32_t)(b * 8 + h) * (uint32_t)L_ + (uint32_t)(lq0 + row0 + CLS_)) * 1024u;

#pragma unroll
        for (int c = 0; c < 4; ++c) {
            // --- QK MFMA for nt = 4c..4c+3 (issued, results pending) ---
#pragma unroll
            for (int u = 0; u < 4; ++u) {
                const int nt = c * 4 + u;
                const int koff = ((wv * 16 + nt) * 16 + mcol) * 1536 + quad * 8;
                f32x4 acc = {0.f, 0.f, 0.f, 0.f};
                acc = __builtin_amdgcn_mfma_f32_16x16x32_bf16(qa0, *(const bf16x8*)&kvb[koff],      acc, 0, 0, 0);
                acc = __builtin_amdgcn_mfma_f32_16x16x32_bf16(qa1, *(const bf16x8*)&kvb[koff + 32], acc, 0, 0, 0);
                acc = __builtin_amdgcn_mfma_f32_16x16x32_bf16(qa2, *(const bf16x8*)&kvb[koff + 64], acc, 0, 0, 0);
                d[nt] = acc;
            }
            // --- threefry for nt = 4c..4c+3 (rolled; hides MFMA latency) ---
#pragma unroll 1
            for (int nt = c * 4; nt < c * 4 + 4; ++nt) {
                const uint32_t col = (uint32_t)(((wv * 16 + nt) << 4) + mcol);
                uint32_t accb = 0u;
#pragma unroll
                for (int rg = 0; rg < 4; ++rg) {
                    uint32_t bits = tf_bits(rowg + 1024u * (uint32_t)rg + col);
                    accb |= (bits < MASK_THR ? 1u : 0u) << rg;
                }
                if (nt < 8) m0 |= accb << (nt * 4);
                else        m1 |= accb << ((nt - 8) * 4);
            }
            // --- exp2 (shift 0) on now-ready accumulators + partial sums ---
#pragma unroll
            for (int u = 0; u < 4; ++u) {
                const int nt = c * 4 + u;
                const bool c_all = (wv == 0 && nt == 0);
                const bool c_few = (wv == 0 && nt == 1);
#pragma unroll
                for (int rg = 0; rg < 4; ++rg) {
                    const bool iscls = c_all || (c_few && mcol < 4);
                    float e = fexp2(d[nt][rg]);
                    d[nt][rg] = e;
                    if (iscls) cs[rg] += e; else ps[rg] += e;
                }
            }
        }
    }

    // ---- cross-lane sum reduce ----
#pragma unroll
    for (int rg = 0; rg < 4; ++rg)
#pragma unroll
        for (int m = 1; m <= 8; m <<= 1) ps[rg] += __shfl_xor(ps[rg], m);
    if (mcol == 0)
#pragma unroll
        for (int rg = 0; rg < 4; ++rg) sS1[wv][row0 + rg] = ps[rg];
    if (wv == 0) {
#pragma unroll
        for (int rg = 0; rg < 4; ++rg)
#pragma unroll
            for (int m = 1; m <= 8; m <<= 1) cs[rg] += __shfl_xor(cs[rg], m);
        if (mcol == 0)
#pragma unroll
            for (int rg = 0; rg < 4; ++rg) sCs[row0 + rg] = cs[rg];
    }
    __syncthreads();

    // 1/S with log2e folded in: e2 = exp2(e1 * (log2e/S)) = exp(p)
    float ipl[4], icl[4];
#pragma unroll
    for (int rg = 0; rg < 4; ++rg) {
        const int rr = row0 + rg;
        float s = sS1[0][rr] + sS1[1][rr] + sS1[2][rr] + sS1[3][rr];
        ipl[rg] = LOG2E_ / s;
        icl[rg] = LOG2E_ / sCs[rr];
    }

    // ---- fused: probs -> mask -> exp (shift 0) -> bf16 store + s2 partials ----
    float s2[4] = {0.f, 0.f, 0.f, 0.f};
#pragma unroll
    for (int nt = 0; nt < 16; ++nt) {
        const bool c_all = (wv == 0 && nt == 0);
        const bool c_few = (wv == 0 && nt == 1);
        const int col = (wv * 16 + nt) * 16 + mcol;
#pragma unroll
        for (int rg = 0; rg < 4; ++rg) {
            const bool iscls = c_all || (c_few && mcol < 4);
            float e2 = fexp2(d[nt][rg] * (iscls ? icl[rg] : ipl[rg]));
            const int i = nt * 4 + rg;
            const uint32_t bit = (i < 32) ? (m0 >> i) : (m1 >> (i - 32));
            e2 = (bit & 1u) ? 0.f : e2;       // == exp(p - 1e12) underflow
            s2[rg] += e2;
            sPb[(row0 + rg) * 1032 + col] = f2bf(e2);
        }
    }
#pragma unroll
    for (int rg = 0; rg < 4; ++rg)
#pragma unroll
        for (int m = 1; m <= 8; m <<= 1) s2[rg] += __shfl_xor(s2[rg], m);
    if (mcol == 0)
#pragma unroll
        for (int rg = 0; rg < 4; ++rg) sS2[wv][row0 + rg] = s2[rg];
    __syncthreads();

    // ---- PV via MFMA: wave wv owns d-tiles {wv, wv+4 (if <6)} ----
    {
        const int t0 = wv, t1 = wv + 4;
        const size_t vbase = ((size_t)(b * 8 + h)) * 96 * 1024;
        f32x4 a0 = {0.f, 0.f, 0.f, 0.f};
        f32x4 a1 = {0.f, 0.f, 0.f, 0.f};
        __builtin_amdgcn_s_setprio(1);
#pragma unroll 4
        for (int k0 = 0; k0 < 1024; k0 += 32) {
            const bf16x8 pa = *(const bf16x8*)&sPb[mcol * 1032 + k0 + quad * 8];
            const size_t v0 = vbase + (size_t)(t0 * 16 + mcol) * 1024 + k0 + quad * 8;
            a0 = __builtin_amdgcn_mfma_f32_16x16x32_bf16(pa, *(const bf16x8*)&vT[v0], a0, 0, 0, 0);
            if (t1 < 6) {
                const size_t v1 = vbase + (size_t)(t1 * 16 + mcol) * 1024 + k0 + quad * 8;
                a1 = __builtin_amdgcn_mfma_f32_16x16x32_bf16(pa, *(const bf16x8*)&vT[v1], a1, 0, 0, 0);
            }
        }
        __builtin_amdgcn_s_setprio(0);

        float inv[4];
#pragma unroll
        for (int rg = 0; rg < 4; ++rg) {
            const int rr = row0 + rg;
            inv[rg] = 1.f / (sS2[0][rr] + sS2[1][rr] + sS2[2][rr] + sS2[3][rr]);
        }
#pragma unroll
        for (int rg = 0; rg < 4; ++rg) {
            const size_t ob = ((size_t)(b * NT) + lq0 + row0 + rg) * 768 + h * 96;
            {
                float val = a0[rg] * inv[rg];
                unsigned short hb = f2bf(val);
                xh[ob + t0 * 16 + mcol] = hb;
                xl[ob + t0 * 16 + mcol] = f2bf(val - __uint_as_float((uint32_t)hb << 16));
            }
            if (t1 < 6) {
                float val = a1[rg] * inv[rg];
                unsigned short hb = f2bf(val);
                xh[ob + t1 * 16 + mcol] = hb;
                xl[ob + t1 * 16 + mcol] = f2bf(val - __uint_as_float((uint32_t)hb << 16));
            }
        }
    }
}

// ---------------------------------------------------------------------------
extern "C" void kernel_launch(void* const* d_in, const int* in_sizes, int n_in,
                              void* d_out, int out_size, void* d_ws, size_t ws_size,
                              hipStream_t stream)
{
    const float* in_q   = (const float*)d_in[0];
    const float* in_k   = (const float*)d_in[1];
    const float* Wq     = (const float*)d_in[2];
    const float* Wkv    = (const float*)d_in[3];
    // d_in[4] = Wcls — unused (cls query rows are dropped by the reference)
    const float* Wproj  = (const float*)d_in[5];
    const float* bproj  = (const float*)d_in[6];
    float* out = (float*)d_out;

    // workspace layout (bf16 units)
    unsigned short* ws16 = (unsigned short*)d_ws;
    unsigned short* Aq   = ws16;                  // 6291456
    unsigned short* Ak   = Aq   + 6291456;        // 6291456
    unsigned short* qb   = Ak   + 6291456;        // 6291456
    unsigned short* kv16 = qb   + 6291456;        // 12582912 (V half unused)
    unsigned short* vT   = kv16 + 12582912;       // 6291456
    unsigned short* Wqt  = vT   + 6291456;        // 589824
    unsigned short* Wkvt = Wqt  + 589824;         // 1179648
    unsigned short* Wpt  = Wkvt + 1179648;        // 589824
    unsigned short* xh   = Aq;                    // reuse (dead after gemm_qkv)
    unsigned short* xl   = Ak;                    // reuse (dead after gemm_qkv)

    dim3 blk(256);

    // SCALE * log2e folded into Wq so QK logits are in exp2 domain
    pre_all<<<15744, blk, 0, stream>>>(
        in_q, Aq, in_k, Ak, Wq, Wkv, Wproj, Wqt, Wkvt, Wpt, SCALE_ * LOG2E_);

    mfma_gemm_qkv<<<1152, blk, 0, stream>>>(
        Aq, Ak, Wqt, Wkvt, qb, kv16, vT);

    attn_kernel<<<4096, blk, 0, stream>>>(qb, kv16, vT, xh, xl);

    mfma_gemm_proj<<<768, blk, 0, stream>>>(
        xh, xl, Wpt, bproj, out);
}